// Round 1
// baseline (124.543 us; speedup 1.0000x reference)
//
#include <hip/hip_runtime.h>
#include <hip/hip_fp16.h>

#define IN_DIM 8192
#define OUT_DIM 8192
#define BATCH 2048
#define TPB 256                      // 4 waves/block; 32KB LDS -> 5 blocks/CU (LDS-limited)
#define NIT (OUT_DIM / 4 / TPB)      // 8 float4-outputs per thread
#define NSTG (IN_DIM / 4 / TPB)      // 8 direct-to-LDS 16B loads per thread

typedef float fvec4 __attribute__((ext_vector_type(4)));

// Direct global->LDS DMA, 16 B per lane. LDS dest is wave-uniform base +
// lane*16 because our layout is linear: tid = 64w+l -> byte off 1024w + 16l.
#define GLOAD_LDS16(gp, lp)                                                        \
    __builtin_amdgcn_global_load_lds(                                              \
        (const __attribute__((address_space(1))) unsigned int*)(gp),               \
        (__attribute__((address_space(3))) unsigned int*)(lp), 16, 0, 0)

// ---------------------------------------------------------------------------
// Kernel 1: softmax(16) -> 4 affine coeffs {1,a,b,ab} in FP32:
//   pidx[j] = (idx_a*4) | (idx_b*4 << 16)   -- BYTE offsets (idx<8192 -> *4 < 32768)
//   pcA[j]  = float2(c0, ca), pcB[j] = float2(cb, cab)
// 128 blocks x 64 so it isn't latency-bound on 1/8 of the CUs; w row = 64 B
// loaded as 4x float4 instead of 16 scalar dwords.
// ---------------------------------------------------------------------------
__global__ __launch_bounds__(64) void coeff_kernel(
    const float* __restrict__ w,
    const int* __restrict__ idx_a,
    const int* __restrict__ idx_b,
    int* __restrict__ pidx,
    float2* __restrict__ pcA,
    float2* __restrict__ pcB)
{
    int j = blockIdx.x * 64 + threadIdx.x;     // grid exact: 8192 = 128*64

    const float4* w4 = (const float4*)(w + (size_t)j * 16);
    float4 q0 = w4[0], q1 = w4[1], q2 = w4[2], q3 = w4[3];
    float wv[16] = { q0.x, q0.y, q0.z, q0.w,
                     q1.x, q1.y, q1.z, q1.w,
                     q2.x, q2.y, q2.z, q2.w,
                     q3.x, q3.y, q3.z, q3.w };

    float m = -1e30f;
#pragma unroll
    for (int k = 0; k < 16; ++k) m = fmaxf(m, wv[k]);
    float s = 0.f;
#pragma unroll
    for (int k = 0; k < 16; ++k) { wv[k] = __expf(wv[k] - m); s += wv[k]; }
    float inv = 1.0f / s;
#pragma unroll
    for (int k = 0; k < 16; ++k) wv[k] *= inv;

    float c0  = wv[8] + wv[9] + wv[10] + wv[11] + wv[12] + wv[13] + wv[14] + wv[15];
    float ca  = wv[2] + wv[3] + wv[6] + wv[7] - wv[8] - wv[9] - wv[12] - wv[13];
    float cb  = wv[4] + wv[5] + wv[6] + wv[7] - wv[8] - wv[9] - wv[10] - wv[11];
    float cab = wv[1] - wv[2] - wv[4] - 2.f * wv[6] - wv[7]
              + wv[8] + 2.f * wv[9] + wv[11] + wv[13] - wv[14];

    pidx[j] = ((idx_a[j] << 2) & 0xffff) | (idx_b[j] << 18);
    pcA[j]  = make_float2(c0, ca);
    pcB[j]  = make_float2(cb, cab);
}

// ---------------------------------------------------------------------------
// Kernel 2: one block per row (grid=2048). x row DMA'd into 32KB LDS via
// global_load_lds (no VGPR roundtrip, no ds_write). Issue order: 8 DMA loads,
// then 5 coeff loads, then s_waitcnt vmcnt(5) + raw s_barrier -- the DMA is
// drained, the coeff loads stay in flight ACROSS the barrier. Depth-1 coeff
// register pipeline; fp32 coeffs (no cvt); 3-FMA factored epilogue.
// launch_bounds(256,5): VGPR cap 102, LDS-limits to 5 blocks/CU.
// ---------------------------------------------------------------------------
__global__ __launch_bounds__(TPB, 5) void logic_kernel(
    const float* __restrict__ x,
    const int* __restrict__ pidx,
    const float2* __restrict__ pcA,
    const float2* __restrict__ pcB,
    float* __restrict__ out)
{
    __shared__ float xrow[IN_DIM];           // 32 KB

    const int row = blockIdx.x;
    const int tid = threadIdx.x;

    // ---- stage this row: 8 x 16B direct-to-LDS DMA per thread ----
    const float* xr = x + (size_t)row * IN_DIM;
#pragma unroll
    for (int i = 0; i < NSTG; ++i)
        GLOAD_LDS16(xr + 4 * (i * TPB + tid), xrow + 4 * (i * TPB + tid));

    asm volatile("" ::: "memory");   // pin: coeff loads must issue AFTER the DMA

    const int4*   pidx4 = (const int4*)pidx;
    const float4* pA4   = (const float4*)pcA;
    const float4* pB4   = (const float4*)pcB;

    // iteration 0 coeffs: issued before the barrier, in flight across it
    int4   pi  = pidx4[tid];
    float4 cA0 = pA4[2 * tid],     cA1 = pA4[2 * tid + 1];
    float4 cB0 = pB4[2 * tid],     cB1 = pB4[2 * tid + 1];

    // wait for the 8 DMA loads only (the 5 coeff loads remain outstanding)
    asm volatile("s_waitcnt vmcnt(5)" ::: "memory");
    __builtin_amdgcn_s_barrier();

    fvec4* out4 = (fvec4*)(out + (size_t)row * OUT_DIM);
    const char* xb = (const char*)xrow;

#pragma unroll
    for (int it = 0; it < NIT; ++it) {
        // prefetch next iteration's coeffs; they fly during this compute
        int4 pin = pi; float4 cA0n = cA0, cA1n = cA1, cB0n = cB0, cB1n = cB1;
        if (it + 1 < NIT) {
            int j4 = (it + 1) * TPB + tid;
            pin  = pidx4[j4];
            cA0n = pA4[2 * j4];     cA1n = pA4[2 * j4 + 1];
            cB0n = pB4[2 * j4];     cB1n = pB4[2 * j4 + 1];
        }

        // byte-offset gathers (pidx holds idx*4 packed in 16-bit halves)
        float a0 = *(const float*)(xb + (pi.x & 0xffff)), b0 = *(const float*)(xb + ((unsigned)pi.x >> 16));
        float a1 = *(const float*)(xb + (pi.y & 0xffff)), b1 = *(const float*)(xb + ((unsigned)pi.y >> 16));
        float a2 = *(const float*)(xb + (pi.z & 0xffff)), b2 = *(const float*)(xb + ((unsigned)pi.z >> 16));
        float a3 = *(const float*)(xb + (pi.w & 0xffff)), b3 = *(const float*)(xb + ((unsigned)pi.w >> 16));

        // o = (c0 + ca*a) + b*(cb + cab*a)   -- 3 FMAs per output
        fvec4 o;
        o.x = fmaf(fmaf(cB0.y, a0, cB0.x), b0, fmaf(cA0.y, a0, cA0.x));
        o.y = fmaf(fmaf(cB0.w, a1, cB0.z), b1, fmaf(cA0.w, a1, cA0.z));
        o.z = fmaf(fmaf(cB1.y, a2, cB1.x), b2, fmaf(cA1.y, a2, cA1.x));
        o.w = fmaf(fmaf(cB1.w, a3, cB1.z), b3, fmaf(cA1.w, a3, cA1.z));
        __builtin_nontemporal_store(o, &out4[it * TPB + tid]);

        pi = pin; cA0 = cA0n; cA1 = cA1n; cB0 = cB0n; cB1 = cB1n;
    }
}

extern "C" void kernel_launch(void* const* d_in, const int* in_sizes, int n_in,
                              void* d_out, int out_size, void* d_ws, size_t ws_size,
                              hipStream_t stream)
{
    const float* x       = (const float*)d_in[0];  // (2048, 8192) fp32
    const float* weights = (const float*)d_in[1];  // (8192, 16)   fp32
    const int*   idx_a   = (const int*)d_in[2];    // (8192,) int32 on device
    const int*   idx_b   = (const int*)d_in[3];    // (8192,) int32 on device
    float* out = (float*)d_out;                    // (2048, 8192) fp32

    int*    pidx = (int*)d_ws;                     // 32 KB
    float2* pcA  = (float2*)(pidx + OUT_DIM);      // 64 KB
    float2* pcB  = pcA + OUT_DIM;                  // 64 KB

    coeff_kernel<<<OUT_DIM / 64, 64, 0, stream>>>(weights, idx_a, idx_b, pidx, pcA, pcB);
    logic_kernel<<<BATCH, TPB, 0, stream>>>(x, pidx, pcA, pcB, out);
}

// Round 2
// 119.248 us; speedup vs baseline: 1.0444x; 1.0444x over previous
//
#include <hip/hip_runtime.h>
#include <hip/hip_fp16.h>

#define IN_DIM 8192
#define OUT_DIM 8192
#define BATCH 2048
#define TPB 512                      // 8 waves/block
#define RPB 4                        // rows per block; grid = 2048/4 = 512 = 2 blocks/CU exactly
#define NQ (OUT_DIM / 4 / TPB)       // 4 float4-output quads per thread per row
#define NSTG (IN_DIM / 4 / TPB)      // 4 direct-to-LDS 16B loads per thread per row

typedef float fvec4 __attribute__((ext_vector_type(4)));

// Direct global->LDS DMA, 16 B per lane. LDS dest must be wave-uniform base +
// lane*16: tid = 64w+l -> byte off 16*(i*TPB + 64w) + 16*l. Linear layout ok.
#define GLOAD_LDS16(gp, lp)                                                        \
    __builtin_amdgcn_global_load_lds(                                              \
        (const __attribute__((address_space(1))) unsigned int*)(gp),               \
        (__attribute__((address_space(3))) unsigned int*)(lp), 16, 0, 0)

// ---------------------------------------------------------------------------
// Kernel 1: softmax(16) -> 4 affine coeffs {1,a,b,ab} in FP32:
//   pidx[j] = (idx_a*4) | (idx_b*4 << 16)   -- BYTE offsets (idx<8192 -> *4 < 32768)
//   pcA[j]  = float2(c0, ca), pcB[j] = float2(cb, cab)
// ---------------------------------------------------------------------------
__global__ __launch_bounds__(64) void coeff_kernel(
    const float* __restrict__ w,
    const int* __restrict__ idx_a,
    const int* __restrict__ idx_b,
    int* __restrict__ pidx,
    float2* __restrict__ pcA,
    float2* __restrict__ pcB)
{
    int j = blockIdx.x * 64 + threadIdx.x;     // grid exact: 8192 = 128*64

    const float4* w4 = (const float4*)(w + (size_t)j * 16);
    float4 q0 = w4[0], q1 = w4[1], q2 = w4[2], q3 = w4[3];
    float wv[16] = { q0.x, q0.y, q0.z, q0.w,
                     q1.x, q1.y, q1.z, q1.w,
                     q2.x, q2.y, q2.z, q2.w,
                     q3.x, q3.y, q3.z, q3.w };

    float m = -1e30f;
#pragma unroll
    for (int k = 0; k < 16; ++k) m = fmaxf(m, wv[k]);
    float s = 0.f;
#pragma unroll
    for (int k = 0; k < 16; ++k) { wv[k] = __expf(wv[k] - m); s += wv[k]; }
    float inv = 1.0f / s;
#pragma unroll
    for (int k = 0; k < 16; ++k) wv[k] *= inv;

    float c0  = wv[8] + wv[9] + wv[10] + wv[11] + wv[12] + wv[13] + wv[14] + wv[15];
    float ca  = wv[2] + wv[3] + wv[6] + wv[7] - wv[8] - wv[9] - wv[12] - wv[13];
    float cb  = wv[4] + wv[5] + wv[6] + wv[7] - wv[8] - wv[9] - wv[10] - wv[11];
    float cab = wv[1] - wv[2] - wv[4] - 2.f * wv[6] - wv[7]
              + wv[8] + 2.f * wv[9] + wv[11] + wv[13] - wv[14];

    pidx[j] = ((idx_a[j] << 2) & 0xffff) | (idx_b[j] << 18);
    pcA[j]  = make_float2(c0, ca);
    pcB[j]  = make_float2(cb, cab);
}

// ---------------------------------------------------------------------------
// Kernel 2: each block owns 4 rows. Coeffs/indices for this thread's 16
// output columns are loaded ONCE into registers (row-invariant!) and reused.
// x rows are double-buffered in LDS via global_load_lds:
//   iter r: waitcnt(counted) -> barrier -> issue DMA(row r+1 -> buf^1)
//           -> compute row r from buf  (DMA flies under a full row of compute)
// vmcnt never drains to 0 in the loop: at iter-r top, outstanding FIFO is
// [DMA(r) x4 oldest, stores(r-1) x4 newest] -> vmcnt(4) retires exactly DMA(r).
// ---------------------------------------------------------------------------
__global__ __launch_bounds__(TPB, 4) void logic_kernel(
    const float* __restrict__ x,
    const int* __restrict__ pidx,
    const float2* __restrict__ pcA,
    const float2* __restrict__ pcB,
    float* __restrict__ out)
{
    __shared__ float xrow[2][IN_DIM];        // 64 KB -> 2 blocks/CU (LDS-limited)

    const int tid  = threadIdx.x;
    const int row0 = blockIdx.x * RPB;

    // ---- load this thread's coeffs ONCE (persist in regs across all rows) ----
    const int4*   pidx4 = (const int4*)pidx;
    const float4* pA4   = (const float4*)pcA;
    const float4* pB4   = (const float4*)pcB;

    int4   pi[NQ];
    float4 cA[2 * NQ];
    float4 cB[2 * NQ];
#pragma unroll
    for (int q = 0; q < NQ; ++q) {
        int j4 = q * TPB + tid;
        pi[q]         = pidx4[j4];
        cA[2 * q]     = pA4[2 * j4];
        cA[2 * q + 1] = pA4[2 * j4 + 1];
        cB[2 * q]     = pB4[2 * j4];
        cB[2 * q + 1] = pB4[2 * j4 + 1];
    }

    // ---- prologue: DMA row0 -> buf0 ----
    {
        const float* xr = x + (size_t)row0 * IN_DIM;
#pragma unroll
        for (int i = 0; i < NSTG; ++i)
            GLOAD_LDS16(xr + 4 * (i * TPB + tid), &xrow[0][4 * (i * TPB + tid)]);
    }

#pragma unroll
    for (int r = 0; r < RPB; ++r) {
        // retire row r's DMA; keep newer vmem (next DMA / old stores) in flight
        if (r == 0) asm volatile("s_waitcnt vmcnt(0)" ::: "memory");
        else        asm volatile("s_waitcnt vmcnt(4)" ::: "memory");
        __builtin_amdgcn_s_barrier();   // all waves' DMA for row r retired -> LDS valid

        // issue next row's DMA into the other buffer; safe: buf^1 was last read
        // in iter r-1 and every wave passed the barrier above after reading it
        if (r + 1 < RPB) {
            const float* xn = x + (size_t)(row0 + r + 1) * IN_DIM;
#pragma unroll
            for (int i = 0; i < NSTG; ++i)
                GLOAD_LDS16(xn + 4 * (i * TPB + tid), &xrow[(r + 1) & 1][4 * (i * TPB + tid)]);
        }
        asm volatile("" ::: "memory");  // pin: DMA issue precedes compute's LDS reads

        const char* xb = (const char*)xrow[r & 1];
        fvec4* out4 = (fvec4*)(out + (size_t)(row0 + r) * OUT_DIM);

#pragma unroll
        for (int q = 0; q < NQ; ++q) {
            int4 p = pi[q];
            // byte-offset gathers (pidx holds idx*4 packed in 16-bit halves)
            float a0 = *(const float*)(xb + (p.x & 0xffff)), b0 = *(const float*)(xb + ((unsigned)p.x >> 16));
            float a1 = *(const float*)(xb + (p.y & 0xffff)), b1 = *(const float*)(xb + ((unsigned)p.y >> 16));
            float a2 = *(const float*)(xb + (p.z & 0xffff)), b2 = *(const float*)(xb + ((unsigned)p.z >> 16));
            float a3 = *(const float*)(xb + (p.w & 0xffff)), b3 = *(const float*)(xb + ((unsigned)p.w >> 16));

            float4 A0 = cA[2 * q], A1 = cA[2 * q + 1];
            float4 B0 = cB[2 * q], B1 = cB[2 * q + 1];

            // o = (c0 + ca*a) + b*(cb + cab*a)   -- 3 FMAs per output
            fvec4 o;
            o.x = fmaf(fmaf(B0.y, a0, B0.x), b0, fmaf(A0.y, a0, A0.x));
            o.y = fmaf(fmaf(B0.w, a1, B0.z), b1, fmaf(A0.w, a1, A0.z));
            o.z = fmaf(fmaf(B1.y, a2, B1.x), b2, fmaf(A1.y, a2, A1.x));
            o.w = fmaf(fmaf(B1.w, a3, B1.z), b3, fmaf(A1.w, a3, A1.z));
            __builtin_nontemporal_store(o, &out4[q * TPB + tid]);
        }
    }
}

extern "C" void kernel_launch(void* const* d_in, const int* in_sizes, int n_in,
                              void* d_out, int out_size, void* d_ws, size_t ws_size,
                              hipStream_t stream)
{
    const float* x       = (const float*)d_in[0];  // (2048, 8192) fp32
    const float* weights = (const float*)d_in[1];  // (8192, 16)   fp32
    const int*   idx_a   = (const int*)d_in[2];    // (8192,) int32 on device
    const int*   idx_b   = (const int*)d_in[3];    // (8192,) int32 on device
    float* out = (float*)d_out;                    // (2048, 8192) fp32

    int*    pidx = (int*)d_ws;                     // 32 KB
    float2* pcA  = (float2*)(pidx + OUT_DIM);      // 64 KB
    float2* pcB  = pcA + OUT_DIM;                  // 64 KB

    coeff_kernel<<<OUT_DIM / 64, 64, 0, stream>>>(weights, idx_a, idx_b, pidx, pcA, pcB);
    logic_kernel<<<BATCH / RPB, TPB, 0, stream>>>(x, pidx, pcA, pcB, out);
}

// Round 3
// 116.781 us; speedup vs baseline: 1.0665x; 1.0211x over previous
//
#include <hip/hip_runtime.h>
#include <hip/hip_fp16.h>

#define IN_DIM 8192
#define OUT_DIM 8192
#define BATCH 2048
#define TPB 512                      // 8 waves/block
#define RPB 4                        // rows per block; grid = 512 = 2 blocks/CU
#define NQ (OUT_DIM / 4 / TPB)       // 4 float4-output quads per thread per row
#define NSTG (IN_DIM / 4 / TPB)      // 4 direct-to-LDS 16B loads per thread per row

typedef float fvec4 __attribute__((ext_vector_type(4)));

#define GLOAD_LDS16(gp, lp)                                                        \
    __builtin_amdgcn_global_load_lds(                                              \
        (const __attribute__((address_space(1))) unsigned int*)(gp),               \
        (__attribute__((address_space(3))) unsigned int*)(lp), 16, 0, 0)

#define MEMFENCE() asm volatile("" ::: "memory")

// ---------------------------------------------------------------------------
// Kernel 1: softmax(16) -> 4 affine coeffs {1,a,b,ab} in FP32:
//   pidx[j] = (idx_a*4) | (idx_b*4 << 16)   -- BYTE offsets (idx<8192 -> *4 < 32768)
//   pcA[j]  = float2(c0, ca), pcB[j] = float2(cb, cab)
// ---------------------------------------------------------------------------
__global__ __launch_bounds__(64) void coeff_kernel(
    const float* __restrict__ w,
    const int* __restrict__ idx_a,
    const int* __restrict__ idx_b,
    int* __restrict__ pidx,
    float2* __restrict__ pcA,
    float2* __restrict__ pcB)
{
    int j = blockIdx.x * 64 + threadIdx.x;     // grid exact: 8192 = 128*64

    const float4* w4 = (const float4*)(w + (size_t)j * 16);
    float4 q0 = w4[0], q1 = w4[1], q2 = w4[2], q3 = w4[3];
    float wv[16] = { q0.x, q0.y, q0.z, q0.w,
                     q1.x, q1.y, q1.z, q1.w,
                     q2.x, q2.y, q2.z, q2.w,
                     q3.x, q3.y, q3.z, q3.w };

    float m = -1e30f;
#pragma unroll
    for (int k = 0; k < 16; ++k) m = fmaxf(m, wv[k]);
    float s = 0.f;
#pragma unroll
    for (int k = 0; k < 16; ++k) { wv[k] = __expf(wv[k] - m); s += wv[k]; }
    float inv = 1.0f / s;
#pragma unroll
    for (int k = 0; k < 16; ++k) wv[k] *= inv;

    float c0  = wv[8] + wv[9] + wv[10] + wv[11] + wv[12] + wv[13] + wv[14] + wv[15];
    float ca  = wv[2] + wv[3] + wv[6] + wv[7] - wv[8] - wv[9] - wv[12] - wv[13];
    float cb  = wv[4] + wv[5] + wv[6] + wv[7] - wv[8] - wv[9] - wv[10] - wv[11];
    float cab = wv[1] - wv[2] - wv[4] - 2.f * wv[6] - wv[7]
              + wv[8] + 2.f * wv[9] + wv[11] + wv[13] - wv[14];

    pidx[j] = ((idx_a[j] << 2) & 0xffff) | (idx_b[j] << 18);
    pcA[j]  = make_float2(c0, ca);
    pcB[j]  = make_float2(cb, cab);
}

// ---------------------------------------------------------------------------
// Kernel 2: 4 rows per block, coeffs register-resident (row-invariant),
// double-buffered LDS staging via global_load_lds with ISSUE-EARLY schedule:
//
//   iter r: bar_A (all waves finished reading buf[(r+1)&1] in iter r-1)
//           issue DMA(row r+1 -> buf[(r+1)&1])        <-- before the wait!
//           s_waitcnt vmcnt(8)  -- retires exactly DMA(r); st(r-1) and
//                                  DMA(r+1) stay in flight across bar_B
//           bar_B (LDS row r valid for all waves)
//           compute row r from buf[r&1], 4x nontemporal float4 stores
//
// Per-wave vmem FIFO at the vmcnt point: [DMA(r) x4 | st(r-1) x4 | DMA(r+1) x4]
//  -> vmcnt(8) is the counted wait. Edges: r==0 -> vmcnt(4) (drains the 20
// coeff loads too, which are older); r==RPB-1 -> vmcnt(4) (no DMA issued).
// DMA(r+1) now has a full row-period of compute+wait to fly instead of zero:
// HBM reads and writes interleave continuously instead of lockstep bursts.
// ---------------------------------------------------------------------------
__global__ __launch_bounds__(TPB, 4) void logic_kernel(
    const float* __restrict__ x,
    const int* __restrict__ pidx,
    const float2* __restrict__ pcA,
    const float2* __restrict__ pcB,
    float* __restrict__ out)
{
    __shared__ float xrow[2][IN_DIM];        // 64 KB -> 2 blocks/CU (LDS-limited)

    const int tid  = threadIdx.x;
    const int row0 = blockIdx.x * RPB;

    // ---- coeffs ONCE into registers (reused for all 4 rows) ----
    const int4*   pidx4 = (const int4*)pidx;
    const float4* pA4   = (const float4*)pcA;
    const float4* pB4   = (const float4*)pcB;

    int4   pi[NQ];
    float4 cA[2 * NQ];
    float4 cB[2 * NQ];
#pragma unroll
    for (int q = 0; q < NQ; ++q) {
        int j4 = q * TPB + tid;
        pi[q]         = pidx4[j4];
        cA[2 * q]     = pA4[2 * j4];
        cA[2 * q + 1] = pA4[2 * j4 + 1];
        cB[2 * q]     = pB4[2 * j4];
        cB[2 * q + 1] = pB4[2 * j4 + 1];
    }
    MEMFENCE();   // coeff loads issued before DMA(0) -- keeps the FIFO math exact

    // ---- prologue: DMA row0 -> buf0 ----
    {
        const float* xr = x + (size_t)row0 * IN_DIM;
#pragma unroll
        for (int i = 0; i < NSTG; ++i)
            GLOAD_LDS16(xr + 4 * (i * TPB + tid), &xrow[0][4 * (i * TPB + tid)]);
    }
    MEMFENCE();

#pragma unroll
    for (int r = 0; r < RPB; ++r) {
        // bar_A: every wave is done READING buf[(r+1)&1] (last read in iter r-1)
        __builtin_amdgcn_s_barrier();

        // issue next row's DMA BEFORE waiting on the current row's DMA
        if (r + 1 < RPB) {
            const float* xn = x + (size_t)(row0 + r + 1) * IN_DIM;
#pragma unroll
            for (int i = 0; i < NSTG; ++i)
                GLOAD_LDS16(xn + 4 * (i * TPB + tid), &xrow[(r + 1) & 1][4 * (i * TPB + tid)]);
        }
        MEMFENCE();

        // counted retire of DMA(r) only (never drain to 0 mid-loop)
        if (r == 0 || r + 1 == RPB) asm volatile("s_waitcnt vmcnt(4)" ::: "memory");
        else                        asm volatile("s_waitcnt vmcnt(8)" ::: "memory");
        __builtin_amdgcn_s_barrier();   // bar_B: LDS row r valid for all waves
        MEMFENCE();

        const char* xb = (const char*)xrow[r & 1];
        fvec4* out4 = (fvec4*)(out + (size_t)(row0 + r) * OUT_DIM);

#pragma unroll
        for (int q = 0; q < NQ; ++q) {
            int4 p = pi[q];
            // byte-offset gathers (pidx holds idx*4 packed in 16-bit halves)
            float a0 = *(const float*)(xb + (p.x & 0xffff)), b0 = *(const float*)(xb + ((unsigned)p.x >> 16));
            float a1 = *(const float*)(xb + (p.y & 0xffff)), b1 = *(const float*)(xb + ((unsigned)p.y >> 16));
            float a2 = *(const float*)(xb + (p.z & 0xffff)), b2 = *(const float*)(xb + ((unsigned)p.z >> 16));
            float a3 = *(const float*)(xb + (p.w & 0xffff)), b3 = *(const float*)(xb + ((unsigned)p.w >> 16));

            float4 A0 = cA[2 * q], A1 = cA[2 * q + 1];
            float4 B0 = cB[2 * q], B1 = cB[2 * q + 1];

            // o = (c0 + ca*a) + b*(cb + cab*a)   -- 3 FMAs per output
            fvec4 o;
            o.x = fmaf(fmaf(B0.y, a0, B0.x), b0, fmaf(A0.y, a0, A0.x));
            o.y = fmaf(fmaf(B0.w, a1, B0.z), b1, fmaf(A0.w, a1, A0.z));
            o.z = fmaf(fmaf(B1.y, a2, B1.x), b2, fmaf(A1.y, a2, A1.x));
            o.w = fmaf(fmaf(B1.w, a3, B1.z), b3, fmaf(A1.w, a3, A1.z));
            __builtin_nontemporal_store(o, &out4[q * TPB + tid]);
        }
        MEMFENCE();
    }
}

extern "C" void kernel_launch(void* const* d_in, const int* in_sizes, int n_in,
                              void* d_out, int out_size, void* d_ws, size_t ws_size,
                              hipStream_t stream)
{
    const float* x       = (const float*)d_in[0];  // (2048, 8192) fp32
    const float* weights = (const float*)d_in[1];  // (8192, 16)   fp32
    const int*   idx_a   = (const int*)d_in[2];    // (8192,) int32 on device
    const int*   idx_b   = (const int*)d_in[3];    // (8192,) int32 on device
    float* out = (float*)d_out;                    // (2048, 8192) fp32

    int*    pidx = (int*)d_ws;                     // 32 KB
    float2* pcA  = (float2*)(pidx + OUT_DIM);      // 64 KB
    float2* pcB  = pcA + OUT_DIM;                  // 64 KB

    coeff_kernel<<<OUT_DIM / 64, 64, 0, stream>>>(weights, idx_a, idx_b, pidx, pcA, pcB);
    logic_kernel<<<BATCH / RPB, TPB, 0, stream>>>(x, pidx, pcA, pcB, out);
}